// Round 1
// baseline (2371.902 us; speedup 1.0000x reference)
//
#include <hip/hip_runtime.h>

#define LAYERS 4
#define BB 16
#define TT 512
#define CC 1024
#define HH 16
#define DD 64
#define VV 32000
#define MM (BB*TT)   // 8192 rows

typedef __attribute__((ext_vector_type(8))) short bf16x8;
typedef __attribute__((ext_vector_type(4))) float f32x4;

__device__ __forceinline__ unsigned short f2b(float f) {
  union { float f; unsigned int u; } v; v.f = f;
  unsigned int r = v.u + 0x7FFFu + ((v.u >> 16) & 1u);
  return (unsigned short)(r >> 16);
}
__device__ __forceinline__ float blo(unsigned int u) {
  union { unsigned int x; float f; } v; v.x = u << 16; return v.f;
}
__device__ __forceinline__ float bhi(unsigned int u) {
  union { unsigned int x; float f; } v; v.x = u & 0xFFFF0000u; return v.f;
}

// ---------------- weight fp32 -> bf16 ----------------
__global__ __launch_bounds__(256) void cvt_kernel(const float* __restrict__ src,
                                                  unsigned short* __restrict__ dst, int n4) {
  int i = blockIdx.x * 256 + threadIdx.x;
  if (i >= n4) return;
  float4 v = ((const float4*)src)[i];
  ushort4 o; o.x = f2b(v.x); o.y = f2b(v.y); o.z = f2b(v.z); o.w = f2b(v.w);
  ((ushort4*)dst)[i] = o;
}

// ---------------- embedding: x = emb[Xm] + pos ----------------
__global__ __launch_bounds__(256) void embed_kernel(const int* __restrict__ X, const int* __restrict__ S,
    const float* __restrict__ emb, const float* __restrict__ pos,
    float* __restrict__ x, unsigned short* __restrict__ xb) {
  int bt = blockIdx.x; int tid = threadIdx.x;
  int t = bt & (TT - 1);
  int tok = S[bt] ? X[bt] : VV;      // Xm = X*S + (1-S)*V
  float4 e = ((const float4*)(emb + (size_t)tok * CC))[tid];
  float4 p = ((const float4*)(pos + (size_t)t * CC))[tid];
  float4 r; r.x = e.x + p.x; r.y = e.y + p.y; r.z = e.z + p.z; r.w = e.w + p.w;
  ((float4*)(x + (size_t)bt * CC))[tid] = r;
  ushort4 ub; ub.x = f2b(r.x); ub.y = f2b(r.y); ub.z = f2b(r.z); ub.w = f2b(r.w);
  ((ushort4*)(xb + (size_t)bt * CC))[tid] = ub;
}

// ---------------- GEMM: out[m,n] = sum_k A[m,k]*W[n,k], epilogue variants ----------------
// EPI 0: out bf16 (qkv)     EPI 1: x += acc, write x f32 + xb bf16 (out-proj residual)
// EPI 2: h = relu(acc+bias) bf16 (ffn1)   EPI 3: x += acc+bias, write x f32 + xb bf16 (ffn2)
__device__ __forceinline__ void gload16(const unsigned short* g, const unsigned short* lds) {
  __builtin_amdgcn_global_load_lds((const __attribute__((address_space(1))) void*)g,
                                   (__attribute__((address_space(3))) void*)lds, 16, 0, 0);
}

template<int EPI>
__global__ __launch_bounds__(256) void gemm_kernel(
    const unsigned short* __restrict__ A,   // M x K bf16
    const unsigned short* __restrict__ W,   // N x K bf16
    float* __restrict__ xres,               // EPI 1,3
    unsigned short* __restrict__ outb,      // bf16 output
    const float* __restrict__ bias,         // EPI 2,3
    int K, int ldc) {
  __shared__ unsigned short As[128 * 64];   // [128 rows][BK=64]
  __shared__ unsigned short Bs[128 * 64];
  const int tid = threadIdx.x;
  const int wv = tid >> 6, ln = tid & 63;
  const int g = ln >> 4, r = ln & 15;
  const int wr = wv >> 1, wc = wv & 1;
  const int brow = blockIdx.y * 128, bcol = blockIdx.x * 128;

  f32x4 acc[4][4];
  #pragma unroll
  for (int i = 0; i < 4; ++i)
    #pragma unroll
    for (int j = 0; j < 4; ++j)
      acc[i][j] = (f32x4){0.f, 0.f, 0.f, 0.f};

  for (int k0 = 0; k0 < K; k0 += 64) {
    // stage A and B tiles: 128x64 bf16 = 16KB each; chunk = 16B
    #pragma unroll
    for (int c4 = 0; c4 < 4; ++c4) {
      int c = (wv * 4 + c4) * 64 + ln;       // chunk id 0..1023
      int row = c >> 3, col = (c & 7) << 3;  // 8 chunks per 64-elem row
      gload16(A + (size_t)(brow + row) * K + k0 + col, As + (size_t)(wv * 4 + c4) * 512);
      gload16(W + (size_t)(bcol + row) * K + k0 + col, Bs + (size_t)(wv * 4 + c4) * 512);
    }
    __syncthreads();   // vmcnt drain + barrier

    bf16x8 av[2][4], bv[2][4];
    #pragma unroll
    for (int kk = 0; kk < 2; ++kk) {
      #pragma unroll
      for (int i = 0; i < 4; ++i) {
        av[kk][i] = *(const bf16x8*)(As + (size_t)(wr * 64 + i * 16 + r) * 64 + kk * 32 + g * 8);
        bv[kk][i] = *(const bf16x8*)(Bs + (size_t)(wc * 64 + i * 16 + r) * 64 + kk * 32 + g * 8);
      }
    }
    #pragma unroll
    for (int kk = 0; kk < 2; ++kk)
      #pragma unroll
      for (int i = 0; i < 4; ++i)
        #pragma unroll
        for (int j = 0; j < 4; ++j)
          acc[i][j] = __builtin_amdgcn_mfma_f32_16x16x32_bf16(av[kk][i], bv[kk][j], acc[i][j], 0, 0, 0);
    __syncthreads();   // all reads done before next stage overwrites
  }

  // epilogue: D row = (lane>>4)*4 + reg, col = lane&15
  #pragma unroll
  for (int i = 0; i < 4; ++i) {
    #pragma unroll
    for (int j = 0; j < 4; ++j) {
      #pragma unroll
      for (int q = 0; q < 4; ++q) {
        int rowg = brow + wr * 64 + i * 16 + g * 4 + q;
        int colg = bcol + wc * 64 + j * 16 + r;
        size_t off = (size_t)rowg * ldc + colg;
        float vacc = acc[i][j][q];
        if (EPI == 0) {
          outb[off] = f2b(vacc);
        } else if (EPI == 1) {
          float nx = xres[off] + vacc;
          xres[off] = nx; outb[off] = f2b(nx);
        } else if (EPI == 2) {
          float hv = vacc + bias[colg];
          hv = hv > 0.f ? hv : 0.f;
          outb[off] = f2b(hv);
        } else {
          float nx = xres[off] + vacc + bias[colg];
          xres[off] = nx; outb[off] = f2b(nx);
        }
      }
    }
  }
}

// ---------------- attention: full softmax, lane-owns-q-row, K/V tiles in LDS ----------------
__global__ __launch_bounds__(256) void attn_kernel(const unsigned short* __restrict__ qkv,
                                                   unsigned short* __restrict__ ob) {
  __shared__ float Ks[128][64];   // 32KB f32 (broadcast reads)
  __shared__ float Vs[128][64];   // 32KB f32
  const int tid = threadIdx.x;
  const int wv = tid >> 6, ln = tid & 63;
  const int bh = blockIdx.x >> 1, half = blockIdx.x & 1;
  const int b = bh >> 4, h = bh & 15;
  const int row = half * 256 + wv * 64 + ln;   // q row owned by this lane

  // load q row (64 bf16), scale by 1/sqrt(D)
  float q[64];
  const size_t qoff = ((size_t)(b * TT + row)) * 3072 + h * 64;
  #pragma unroll
  for (int d0 = 0; d0 < 64; d0 += 8) {
    uint4 u = *(const uint4*)(qkv + qoff + d0);
    q[d0 + 0] = blo(u.x) * 0.125f; q[d0 + 1] = bhi(u.x) * 0.125f;
    q[d0 + 2] = blo(u.y) * 0.125f; q[d0 + 3] = bhi(u.y) * 0.125f;
    q[d0 + 4] = blo(u.z) * 0.125f; q[d0 + 5] = bhi(u.z) * 0.125f;
    q[d0 + 6] = blo(u.w) * 0.125f; q[d0 + 7] = bhi(u.w) * 0.125f;
  }

  float oa[64];
  #pragma unroll
  for (int d = 0; d < 64; ++d) oa[d] = 0.f;
  float mrun = -1e30f, ssum = 0.f;

  for (int kt = 0; kt < TT; kt += 128) {
    __syncthreads();
    // stage K (f32) and V (f32) tiles: 128 keys x 64
    #pragma unroll
    for (int i = 0; i < 4; ++i) {
      int c = i * 256 + tid;                 // chunk 0..1023, 8 bf16 each
      int rk = c >> 3, c8 = (c & 7) << 3;
      size_t kofs = ((size_t)(b * TT + kt + rk)) * 3072 + 1024 + h * 64 + c8;
      uint4 ku = *(const uint4*)(qkv + kofs);
      uint4 vu = *(const uint4*)(qkv + kofs + 1024);
      float* kd = &Ks[rk][c8];
      kd[0] = blo(ku.x); kd[1] = bhi(ku.x); kd[2] = blo(ku.y); kd[3] = bhi(ku.y);
      kd[4] = blo(ku.z); kd[5] = bhi(ku.z); kd[6] = blo(ku.w); kd[7] = bhi(ku.w);
      float* vd = &Vs[rk][c8];
      vd[0] = blo(vu.x); vd[1] = bhi(vu.x); vd[2] = blo(vu.y); vd[3] = bhi(vu.y);
      vd[4] = blo(vu.z); vd[5] = bhi(vu.z); vd[6] = blo(vu.w); vd[7] = bhi(vu.w);
    }
    __syncthreads();

    for (int c16 = 0; c16 < 128; c16 += 16) {   // chunks of 16 keys
      float s[16];
      #pragma unroll
      for (int j = 0; j < 16; ++j) {
        const float4* kr = (const float4*)&Ks[c16 + j][0];
        float a0 = 0.f;
        #pragma unroll
        for (int d4 = 0; d4 < 16; ++d4) {
          float4 kv = kr[d4];
          a0 = fmaf(q[4 * d4 + 0], kv.x, a0);
          a0 = fmaf(q[4 * d4 + 1], kv.y, a0);
          a0 = fmaf(q[4 * d4 + 2], kv.z, a0);
          a0 = fmaf(q[4 * d4 + 3], kv.w, a0);
        }
        s[j] = a0;
      }
      float cmax = s[0];
      #pragma unroll
      for (int j = 1; j < 16; ++j) cmax = fmaxf(cmax, s[j]);
      float mn = fmaxf(mrun, cmax);
      float corr = __expf(mrun - mn);
      ssum *= corr;
      #pragma unroll
      for (int d = 0; d < 64; ++d) oa[d] *= corr;
      #pragma unroll
      for (int j = 0; j < 16; ++j) {
        float p = __expf(s[j] - mn);
        ssum += p;
        const float4* vr = (const float4*)&Vs[c16 + j][0];
        #pragma unroll
        for (int d4 = 0; d4 < 16; ++d4) {
          float4 vvv = vr[d4];
          oa[4 * d4 + 0] = fmaf(p, vvv.x, oa[4 * d4 + 0]);
          oa[4 * d4 + 1] = fmaf(p, vvv.y, oa[4 * d4 + 1]);
          oa[4 * d4 + 2] = fmaf(p, vvv.z, oa[4 * d4 + 2]);
          oa[4 * d4 + 3] = fmaf(p, vvv.w, oa[4 * d4 + 3]);
        }
      }
      mrun = mn;
    }
  }

  float inv = 1.f / ssum;
  size_t ooff = ((size_t)(b * TT + row)) * CC + h * 64;
  #pragma unroll
  for (int d0 = 0; d0 < 64; d0 += 4) {
    ushort4 u;
    u.x = f2b(oa[d0 + 0] * inv); u.y = f2b(oa[d0 + 1] * inv);
    u.z = f2b(oa[d0 + 2] * inv); u.w = f2b(oa[d0 + 3] * inv);
    *(ushort4*)(ob + ooff + d0) = u;
  }
}

// ---------------- final: out[b,c] = sum_t x[b,t,c] * I[b,t] ----------------
__global__ __launch_bounds__(256) void final_kernel(const float* __restrict__ x,
                                                    const float* __restrict__ I,
                                                    float* __restrict__ out) {
  int b = blockIdx.x >> 2;
  int c = ((blockIdx.x & 3) << 8) + threadIdx.x;
  float acc = 0.f;
  const float* xp = x + (size_t)b * TT * CC + c;
  const float* Ip = I + (size_t)b * TT;
  for (int t = 0; t < TT; ++t) acc = fmaf(xp[(size_t)t * CC], Ip[t], acc);
  out[b * CC + c] = acc;
}

extern "C" void kernel_launch(void* const* d_in, const int* in_sizes, int n_in,
                              void* d_out, int out_size, void* d_ws, size_t ws_size,
                              hipStream_t stream) {
  const int*   X      = (const int*)d_in[0];
  const float* I      = (const float*)d_in[1];
  const int*   S      = (const int*)d_in[2];
  const float* emb    = (const float*)d_in[3];
  const float* pos    = (const float*)d_in[4];
  const float* qkv_w  = (const float*)d_in[5];
  const float* out_w  = (const float*)d_in[6];
  const float* ffn_w1 = (const float*)d_in[7];
  const float* ffn_b1 = (const float*)d_in[8];
  const float* ffn_w2 = (const float*)d_in[9];
  const float* ffn_b2 = (const float*)d_in[10];
  float* out = (float*)d_out;

  char* ws = (char*)d_ws;
  size_t off = 0;
  auto walloc = [&](size_t bytes) { char* p = ws + off; off += (bytes + 255) & ~(size_t)255; return p; };
  unsigned short* wqkv = (unsigned short*)walloc((size_t)LAYERS * 3 * CC * CC * 2);
  unsigned short* wo   = (unsigned short*)walloc((size_t)LAYERS * CC * CC * 2);
  unsigned short* w1   = (unsigned short*)walloc((size_t)LAYERS * CC * CC * 2);
  unsigned short* w2   = (unsigned short*)walloc((size_t)LAYERS * CC * CC * 2);
  float*          x    = (float*)walloc((size_t)MM * CC * 4);
  unsigned short* xb   = (unsigned short*)walloc((size_t)MM * CC * 2);
  unsigned short* qkvb = (unsigned short*)walloc((size_t)MM * 3 * CC * 2);
  unsigned short* obuf = (unsigned short*)walloc((size_t)MM * CC * 2);
  unsigned short* hbuf = (unsigned short*)walloc((size_t)MM * CC * 2);
  if (off > ws_size) return;  // workspace too small; fail loudly via wrong output

  int n4;
  n4 = LAYERS * 3 * CC * CC / 4; cvt_kernel<<<(n4 + 255) / 256, 256, 0, stream>>>(qkv_w, wqkv, n4);
  n4 = LAYERS * CC * CC / 4;     cvt_kernel<<<(n4 + 255) / 256, 256, 0, stream>>>(out_w, wo, n4);
  n4 = LAYERS * CC * CC / 4;     cvt_kernel<<<(n4 + 255) / 256, 256, 0, stream>>>(ffn_w1, w1, n4);
  n4 = LAYERS * CC * CC / 4;     cvt_kernel<<<(n4 + 255) / 256, 256, 0, stream>>>(ffn_w2, w2, n4);

  embed_kernel<<<MM, 256, 0, stream>>>(X, S, emb, pos, x, xb);

  for (int l = 0; l < LAYERS; ++l) {
    gemm_kernel<0><<<dim3(3 * CC / 128, MM / 128), 256, 0, stream>>>(
        xb, wqkv + (size_t)l * 3 * CC * CC, nullptr, qkvb, nullptr, CC, 3 * CC);
    attn_kernel<<<BB * HH * 2, 256, 0, stream>>>(qkvb, obuf);
    gemm_kernel<1><<<dim3(CC / 128, MM / 128), 256, 0, stream>>>(
        obuf, wo + (size_t)l * CC * CC, x, xb, nullptr, CC, CC);
    gemm_kernel<2><<<dim3(CC / 128, MM / 128), 256, 0, stream>>>(
        xb, w1 + (size_t)l * CC * CC, nullptr, hbuf, ffn_b1 + l * CC, CC, CC);
    gemm_kernel<3><<<dim3(CC / 128, MM / 128), 256, 0, stream>>>(
        hbuf, w2 + (size_t)l * CC * CC, x, xb, ffn_b2 + l * CC, CC, CC);
  }

  final_kernel<<<BB * 4, 256, 0, stream>>>(x, I, out);
}

// Round 2
// 969.921 us; speedup vs baseline: 2.4455x; 2.4455x over previous
//
#include <hip/hip_runtime.h>
#include <stdint.h>

#define LAYERS 4
#define BB 16
#define TT 512
#define CC 1024
#define HH 16
#define DD 64
#define VV 32000
#define MM (BB*TT)   // 8192 rows

typedef __attribute__((ext_vector_type(8))) short bf16x8;
typedef __attribute__((ext_vector_type(4))) float f32x4;
typedef __attribute__((ext_vector_type(16))) float f32x16;

__device__ __forceinline__ unsigned short f2b(float f) {
  union { float f; unsigned int u; } v; v.f = f;
  unsigned int r = v.u + 0x7FFFu + ((v.u >> 16) & 1u);
  return (unsigned short)(r >> 16);
}
__device__ __forceinline__ float blo(unsigned int u) {
  union { unsigned int x; float f; } v; v.x = u << 16; return v.f;
}
__device__ __forceinline__ float bhi(unsigned int u) {
  union { unsigned int x; float f; } v; v.x = u & 0xFFFF0000u; return v.f;
}
__device__ __forceinline__ uint32_t pkbf(float lo, float hi) {
  uint32_t d; asm("v_cvt_pk_bf16_f32 %0, %1, %2" : "=v"(d) : "v"(lo), "v"(hi)); return d;
}
__device__ __forceinline__ float ex2(float x) {
  float r; asm("v_exp_f32 %0, %1" : "=v"(r) : "v"(x)); return r;
}

// ---------------- weight fp32 -> bf16 ----------------
__global__ __launch_bounds__(256) void cvt_kernel(const float* __restrict__ src,
                                                  unsigned short* __restrict__ dst, int n4) {
  int i = blockIdx.x * 256 + threadIdx.x;
  if (i >= n4) return;
  float4 v = ((const float4*)src)[i];
  ushort4 o; o.x = f2b(v.x); o.y = f2b(v.y); o.z = f2b(v.z); o.w = f2b(v.w);
  ((ushort4*)dst)[i] = o;
}

// ---------------- embedding: x = emb[Xm] + pos ----------------
__global__ __launch_bounds__(256) void embed_kernel(const int* __restrict__ X, const int* __restrict__ S,
    const float* __restrict__ emb, const float* __restrict__ pos,
    float* __restrict__ x, unsigned short* __restrict__ xb) {
  int bt = blockIdx.x; int tid = threadIdx.x;
  int t = bt & (TT - 1);
  int tok = S[bt] ? X[bt] : VV;
  float4 e = ((const float4*)(emb + (size_t)tok * CC))[tid];
  float4 p = ((const float4*)(pos + (size_t)t * CC))[tid];
  float4 r; r.x = e.x + p.x; r.y = e.y + p.y; r.z = e.z + p.z; r.w = e.w + p.w;
  ((float4*)(x + (size_t)bt * CC))[tid] = r;
  ushort4 ub; ub.x = f2b(r.x); ub.y = f2b(r.y); ub.z = f2b(r.z); ub.w = f2b(r.w);
  ((ushort4*)(xb + (size_t)bt * CC))[tid] = ub;
}

// ---------------- GEMM (unchanged from R1) ----------------
__device__ __forceinline__ void gload16(const unsigned short* g, const unsigned short* lds) {
  __builtin_amdgcn_global_load_lds((const __attribute__((address_space(1))) void*)g,
                                   (__attribute__((address_space(3))) void*)lds, 16, 0, 0);
}

template<int EPI>
__global__ __launch_bounds__(256) void gemm_kernel(
    const unsigned short* __restrict__ A,
    const unsigned short* __restrict__ W,
    float* __restrict__ xres,
    unsigned short* __restrict__ outb,
    const float* __restrict__ bias,
    int K, int ldc) {
  __shared__ unsigned short As[128 * 64];
  __shared__ unsigned short Bs[128 * 64];
  const int tid = threadIdx.x;
  const int wv = tid >> 6, ln = tid & 63;
  const int g = ln >> 4, r = ln & 15;
  const int wr = wv >> 1, wc = wv & 1;
  const int brow = blockIdx.y * 128, bcol = blockIdx.x * 128;

  f32x4 acc[4][4];
  #pragma unroll
  for (int i = 0; i < 4; ++i)
    #pragma unroll
    for (int j = 0; j < 4; ++j)
      acc[i][j] = (f32x4){0.f, 0.f, 0.f, 0.f};

  for (int k0 = 0; k0 < K; k0 += 64) {
    #pragma unroll
    for (int c4 = 0; c4 < 4; ++c4) {
      int c = (wv * 4 + c4) * 64 + ln;
      int row = c >> 3, col = (c & 7) << 3;
      gload16(A + (size_t)(brow + row) * K + k0 + col, As + (size_t)(wv * 4 + c4) * 512);
      gload16(W + (size_t)(bcol + row) * K + k0 + col, Bs + (size_t)(wv * 4 + c4) * 512);
    }
    __syncthreads();

    bf16x8 av[2][4], bv[2][4];
    #pragma unroll
    for (int kk = 0; kk < 2; ++kk) {
      #pragma unroll
      for (int i = 0; i < 4; ++i) {
        av[kk][i] = *(const bf16x8*)(As + (size_t)(wr * 64 + i * 16 + r) * 64 + kk * 32 + g * 8);
        bv[kk][i] = *(const bf16x8*)(Bs + (size_t)(wc * 64 + i * 16 + r) * 64 + kk * 32 + g * 8);
      }
    }
    #pragma unroll
    for (int kk = 0; kk < 2; ++kk)
      #pragma unroll
      for (int i = 0; i < 4; ++i)
        #pragma unroll
        for (int j = 0; j < 4; ++j)
          acc[i][j] = __builtin_amdgcn_mfma_f32_16x16x32_bf16(av[kk][i], bv[kk][j], acc[i][j], 0, 0, 0);
    __syncthreads();
  }

  #pragma unroll
  for (int i = 0; i < 4; ++i) {
    #pragma unroll
    for (int j = 0; j < 4; ++j) {
      #pragma unroll
      for (int q = 0; q < 4; ++q) {
        int rowg = brow + wr * 64 + i * 16 + g * 4 + q;
        int colg = bcol + wc * 64 + j * 16 + r;
        size_t off = (size_t)rowg * ldc + colg;
        float vacc = acc[i][j][q];
        if (EPI == 0) {
          outb[off] = f2b(vacc);
        } else if (EPI == 1) {
          float nx = xres[off] + vacc;
          xres[off] = nx; outb[off] = f2b(nx);
        } else if (EPI == 2) {
          float hv = vacc + bias[colg];
          hv = hv > 0.f ? hv : 0.f;
          outb[off] = f2b(hv);
        } else {
          float nx = xres[off] + vacc + bias[colg];
          xres[off] = nx; outb[off] = f2b(nx);
        }
      }
    }
  }
}

// ---------------- MFMA flash attention (swapped QK^T, 32x32) ----------------
// Block: 4 waves x 32 q-rows = 128 q-rows of one (b,h). KV tiles of 64.
// S^T = mfma(K, Q): lane holds P[k...][q=lane&31]. P->bf16 via cvt_pk + permlane32_swap.
// O^T = mfma(V^T, P^T) with V^T staged (transposed+swizzled) in LDS.

template<int E>
__device__ __forceinline__ bf16x8 buildP(const f32x16& p) {
  uint32_t a = pkbf(p[E + 0], p[E + 1]);
  uint32_t b = pkbf(p[E + 4], p[E + 5]);
  uint32_t c = pkbf(p[E + 2], p[E + 3]);
  uint32_t d = pkbf(p[E + 6], p[E + 7]);
  asm("v_permlane32_swap_b32 %0, %1" : "+v"(a), "+v"(b));
  asm("v_permlane32_swap_b32 %0, %1" : "+v"(c), "+v"(d));
  union { uint32_t u[4]; bf16x8 v; } r;
  r.u[0] = a; r.u[1] = c; r.u[2] = b; r.u[3] = d;
  return r.v;
}

__global__ __launch_bounds__(256) void attn_kernel(const unsigned short* __restrict__ qkv,
                                                   unsigned short* __restrict__ ob) {
  __shared__ unsigned short Kl[64 * 64];  // [k][d], 16B-chunk pos XOR-swizzled by sigma(k)
  __shared__ unsigned short Vt[64 * 64];  // [d][k], swizzled by sigma(d)
  const int tid = threadIdx.x;
  const int wv = tid >> 6, ln = tid & 63;
  const int lq = ln & 31, hi = ln >> 5;
  const int qt = blockIdx.x >> 8, bh = blockIdx.x & 255;   // bh fastest -> same-KV blocks share XCD
  const int b = bh >> 4, h = bh & 15;
  const int qrow = qt * 128 + wv * 32 + lq;
  const size_t rowQ = (size_t)(b * TT + qrow) * 3072 + h * 64;

  // Q fragments, pre-scaled by (1/sqrt(D)) * log2(e) so p = exp2(s - m)
  const float cs = 0.125f * 1.44269504f;
  bf16x8 qf[4];
  #pragma unroll
  for (int t = 0; t < 4; ++t) {
    uint4 u = *(const uint4*)(qkv + rowQ + t * 16 + hi * 8);
    uint32_t w[4] = {u.x, u.y, u.z, u.w};
    union { uint32_t u4[4]; bf16x8 v; } cv;
    #pragma unroll
    for (int j = 0; j < 4; ++j) cv.u4[j] = pkbf(blo(w[j]) * cs, bhi(w[j]) * cs);
    qf[t] = cv.v;
  }

  f32x16 o0 = {}, o1 = {};
  float mrun = -3.0e38f, lsum = 0.f;

  for (int kv0 = 0; kv0 < TT; kv0 += 64) {
    if (kv0) __syncthreads();
    // --- stage K via global_load_lds, source pre-swizzled ---
    #pragma unroll
    for (int r = 0; r < 2; ++r) {
      int ch = r * 256 + tid;
      int k = ch >> 3, cc = ch & 7;
      int sg = (k & 7) ^ (k >> 3);
      const unsigned short* gs = qkv + (size_t)(b * TT + kv0 + k) * 3072 + 1024 + h * 64 + ((cc ^ sg) << 3);
      gload16(gs, Kl + (size_t)(r * 256 + wv * 64) * 8);
    }
    // --- stage V transposed: thread packs k-pairs into dwords of V^T rows ---
    {
      int cc = tid & 7, kp = tid >> 3;
      int k = kp * 2;
      const unsigned short* gv = qkv + (size_t)(b * TT + kv0 + k) * 3072 + 2048 + h * 64 + cc * 8;
      uint4 g1 = *(const uint4*)gv;
      uint4 g2 = *(const uint4*)(gv + 3072);
      uint32_t w1[4] = {g1.x, g1.y, g1.z, g1.w}, w2[4] = {g2.x, g2.y, g2.z, g2.w};
      #pragma unroll
      for (int j = 0; j < 8; ++j) {
        int d = cc * 8 + j;
        uint32_t dw = (j & 1) ? ((w1[j >> 1] >> 16) | (w2[j >> 1] & 0xFFFF0000u))
                              : ((w1[j >> 1] & 0xFFFFu) | (w2[j >> 1] << 16));
        int sg = (d & 7) ^ (d >> 3);
        *(uint32_t*)(Vt + d * 64 + (k ^ (sg << 3))) = dw;
      }
    }
    __syncthreads();

    // --- S^T = K · Q^T : D[k][q], 2 k-tiles of 32 ---
    f32x16 s0 = {}, s1 = {};
    #pragma unroll
    for (int t = 0; t < 4; ++t) {
      int r0 = lq, r1 = 32 + lq;
      bf16x8 a0 = *(const bf16x8*)(Kl + r0 * 64 + ((((t << 1) | hi) ^ ((r0 & 7) ^ (r0 >> 3))) << 3));
      bf16x8 a1 = *(const bf16x8*)(Kl + r1 * 64 + ((((t << 1) | hi) ^ ((r1 & 7) ^ (r1 >> 3))) << 3));
      s0 = __builtin_amdgcn_mfma_f32_32x32x16_bf16(a0, qf[t], s0, 0, 0, 0);
      s1 = __builtin_amdgcn_mfma_f32_32x32x16_bf16(a1, qf[t], s1, 0, 0, 0);
    }

    // --- online softmax (scaled-log2 domain); lane holds 32 of 64 k's for q=lq ---
    float mx = s0[0];
    #pragma unroll
    for (int r = 1; r < 16; ++r) mx = fmaxf(mx, s0[r]);
    #pragma unroll
    for (int r = 0; r < 16; ++r) mx = fmaxf(mx, s1[r]);
    mx = fmaxf(mx, __shfl_xor(mx, 32));
    float mnew = fmaxf(mrun, mx);
    float cf = ex2(mrun - mnew);
    mrun = mnew;
    lsum *= cf;
    #pragma unroll
    for (int r = 0; r < 16; ++r) { o0[r] *= cf; o1[r] *= cf; }
    #pragma unroll
    for (int r = 0; r < 16; ++r) {
      s0[r] = ex2(s0[r] - mnew);
      s1[r] = ex2(s1[r] - mnew);
      lsum += s0[r] + s1[r];
    }

    // --- P fragments (bf16, PV B-operand) via cvt_pk + permlane32_swap ---
    bf16x8 pf0 = buildP<0>(s0);
    bf16x8 pf1 = buildP<8>(s0);
    bf16x8 pf2 = buildP<0>(s1);
    bf16x8 pf3 = buildP<8>(s1);

    // --- O^T += V^T · P^T : D[d][q], 2 d-tiles of 32 ---
    #pragma unroll
    for (int t = 0; t < 4; ++t) {
      bf16x8 pf = (t == 0) ? pf0 : (t == 1) ? pf1 : (t == 2) ? pf2 : pf3;
      int d0 = lq, d1 = 32 + lq;
      bf16x8 v0 = *(const bf16x8*)(Vt + d0 * 64 + ((((t << 1) | hi) ^ ((d0 & 7) ^ (d0 >> 3))) << 3));
      bf16x8 v1 = *(const bf16x8*)(Vt + d1 * 64 + ((((t << 1) | hi) ^ ((d1 & 7) ^ (d1 >> 3))) << 3));
      o0 = __builtin_amdgcn_mfma_f32_32x32x16_bf16(v0, pf, o0, 0, 0, 0);
      o1 = __builtin_amdgcn_mfma_f32_32x32x16_bf16(v1, pf, o1, 0, 0, 0);
    }
  }

  lsum += __shfl_xor(lsum, 32);
  float inv = 1.f / lsum;
  size_t orow = (size_t)(b * TT + qrow) * CC + h * 64;
  #pragma unroll
  for (int md = 0; md < 2; ++md) {
    #pragma unroll
    for (int rq = 0; rq < 4; ++rq) {
      int d0 = md * 32 + rq * 8 + hi * 4;
      float e0 = (md ? o1[rq * 4 + 0] : o0[rq * 4 + 0]) * inv;
      float e1 = (md ? o1[rq * 4 + 1] : o0[rq * 4 + 1]) * inv;
      float e2 = (md ? o1[rq * 4 + 2] : o0[rq * 4 + 2]) * inv;
      float e3 = (md ? o1[rq * 4 + 3] : o0[rq * 4 + 3]) * inv;
      uint2 st; st.x = pkbf(e0, e1); st.y = pkbf(e2, e3);
      *(uint2*)(ob + orow + d0) = st;
    }
  }
}

// ---------------- final: out[b,c] = sum_t x[b,t,c] * I[b,t] ----------------
__global__ __launch_bounds__(256) void final_kernel(const float* __restrict__ x,
                                                    const float* __restrict__ I,
                                                    float* __restrict__ out) {
  int b = blockIdx.x >> 2;
  int c = ((blockIdx.x & 3) << 8) + threadIdx.x;
  float acc = 0.f;
  const float* xp = x + (size_t)b * TT * CC + c;
  const float* Ip = I + (size_t)b * TT;
  for (int t = 0; t < TT; ++t) acc = fmaf(xp[(size_t)t * CC], Ip[t], acc);
  out[b * CC + c] = acc;
}

extern "C" void kernel_launch(void* const* d_in, const int* in_sizes, int n_in,
                              void* d_out, int out_size, void* d_ws, size_t ws_size,
                              hipStream_t stream) {
  const int*   X      = (const int*)d_in[0];
  const float* I      = (const float*)d_in[1];
  const int*   S      = (const int*)d_in[2];
  const float* emb    = (const float*)d_in[3];
  const float* pos    = (const float*)d_in[4];
  const float* qkv_w  = (const float*)d_in[5];
  const float* out_w  = (const float*)d_in[6];
  const float* ffn_w1 = (const float*)d_in[7];
  const float* ffn_b1 = (const float*)d_in[8];
  const float* ffn_w2 = (const float*)d_in[9];
  const float* ffn_b2 = (const float*)d_in[10];
  float* out = (float*)d_out;

  char* ws = (char*)d_ws;
  size_t off = 0;
  auto walloc = [&](size_t bytes) { char* p = ws + off; off += (bytes + 255) & ~(size_t)255; return p; };
  unsigned short* wqkv = (unsigned short*)walloc((size_t)LAYERS * 3 * CC * CC * 2);
  unsigned short* wo   = (unsigned short*)walloc((size_t)LAYERS * CC * CC * 2);
  unsigned short* w1   = (unsigned short*)walloc((size_t)LAYERS * CC * CC * 2);
  unsigned short* w2   = (unsigned short*)walloc((size_t)LAYERS * CC * CC * 2);
  float*          x    = (float*)walloc((size_t)MM * CC * 4);
  unsigned short* xb   = (unsigned short*)walloc((size_t)MM * CC * 2);
  unsigned short* qkvb = (unsigned short*)walloc((size_t)MM * 3 * CC * 2);
  unsigned short* obuf = (unsigned short*)walloc((size_t)MM * CC * 2);
  unsigned short* hbuf = (unsigned short*)walloc((size_t)MM * CC * 2);
  if (off > ws_size) return;

  int n4;
  n4 = LAYERS * 3 * CC * CC / 4; cvt_kernel<<<(n4 + 255) / 256, 256, 0, stream>>>(qkv_w, wqkv, n4);
  n4 = LAYERS * CC * CC / 4;     cvt_kernel<<<(n4 + 255) / 256, 256, 0, stream>>>(out_w, wo, n4);
  n4 = LAYERS * CC * CC / 4;     cvt_kernel<<<(n4 + 255) / 256, 256, 0, stream>>>(ffn_w1, w1, n4);
  n4 = LAYERS * CC * CC / 4;     cvt_kernel<<<(n4 + 255) / 256, 256, 0, stream>>>(ffn_w2, w2, n4);

  embed_kernel<<<MM, 256, 0, stream>>>(X, S, emb, pos, x, xb);

  for (int l = 0; l < LAYERS; ++l) {
    gemm_kernel<0><<<dim3(3 * CC / 128, MM / 128), 256, 0, stream>>>(
        xb, wqkv + (size_t)l * 3 * CC * CC, nullptr, qkvb, nullptr, CC, 3 * CC);
    attn_kernel<<<4 * 256, 256, 0, stream>>>(qkvb, obuf);
    gemm_kernel<1><<<dim3(CC / 128, MM / 128), 256, 0, stream>>>(
        obuf, wo + (size_t)l * CC * CC, x, xb, nullptr, CC, CC);
    gemm_kernel<2><<<dim3(CC / 128, MM / 128), 256, 0, stream>>>(
        xb, w1 + (size_t)l * CC * CC, nullptr, hbuf, ffn_b1 + l * CC, CC, CC);
    gemm_kernel<3><<<dim3(CC / 128, MM / 128), 256, 0, stream>>>(
        hbuf, w2 + (size_t)l * CC * CC, x, xb, ffn_b2 + l * CC, CC, CC);
  }

  final_kernel<<<BB * 4, 256, 0, stream>>>(x, I, out);
}

// Round 3
// 882.517 us; speedup vs baseline: 2.6877x; 1.0990x over previous
//
#include <hip/hip_runtime.h>
#include <stdint.h>

#define LAYERS 4
#define BB 16
#define TT 512
#define CC 1024
#define HH 16
#define DD 64
#define VV 32000
#define MM (BB*TT)   // 8192 rows

typedef __attribute__((ext_vector_type(8))) short bf16x8;
typedef __attribute__((ext_vector_type(4))) float f32x4;
typedef __attribute__((ext_vector_type(16))) float f32x16;

__device__ __forceinline__ unsigned short f2b(float f) {
  union { float f; unsigned int u; } v; v.f = f;
  unsigned int r = v.u + 0x7FFFu + ((v.u >> 16) & 1u);
  return (unsigned short)(r >> 16);
}
__device__ __forceinline__ float blo(unsigned int u) {
  union { unsigned int x; float f; } v; v.x = u << 16; return v.f;
}
__device__ __forceinline__ float bhi(unsigned int u) {
  union { unsigned int x; float f; } v; v.x = u & 0xFFFF0000u; return v.f;
}
__device__ __forceinline__ uint32_t pkbf(float lo, float hi) {
  uint32_t d; asm("v_cvt_pk_bf16_f32 %0, %1, %2" : "=v"(d) : "v"(lo), "v"(hi)); return d;
}
__device__ __forceinline__ float ex2(float x) {
  float r; asm("v_exp_f32 %0, %1" : "=v"(r) : "v"(x)); return r;
}
__device__ __forceinline__ void gload16(const unsigned short* g, const unsigned short* lds) {
  __builtin_amdgcn_global_load_lds((const __attribute__((address_space(1))) void*)g,
                                   (__attribute__((address_space(3))) void*)lds, 16, 0, 0);
}

// ---------------- weight fp32 -> bf16 ----------------
__global__ __launch_bounds__(256) void cvt_kernel(const float* __restrict__ src,
                                                  unsigned short* __restrict__ dst, int n4) {
  int i = blockIdx.x * 256 + threadIdx.x;
  if (i >= n4) return;
  float4 v = ((const float4*)src)[i];
  ushort4 o; o.x = f2b(v.x); o.y = f2b(v.y); o.z = f2b(v.z); o.w = f2b(v.w);
  ((ushort4*)dst)[i] = o;
}

// ---------------- embedding: x = emb[Xm] + pos ----------------
__global__ __launch_bounds__(256) void embed_kernel(const int* __restrict__ X, const int* __restrict__ S,
    const float* __restrict__ emb, const float* __restrict__ pos,
    float* __restrict__ x, unsigned short* __restrict__ xb) {
  int bt = blockIdx.x; int tid = threadIdx.x;
  int t = bt & (TT - 1);
  int tok = S[bt] ? X[bt] : VV;
  float4 e = ((const float4*)(emb + (size_t)tok * CC))[tid];
  float4 p = ((const float4*)(pos + (size_t)t * CC))[tid];
  float4 r; r.x = e.x + p.x; r.y = e.y + p.y; r.z = e.z + p.z; r.w = e.w + p.w;
  ((float4*)(x + (size_t)bt * CC))[tid] = r;
  ushort4 ub; ub.x = f2b(r.x); ub.y = f2b(r.y); ub.z = f2b(r.z); ub.w = f2b(r.w);
  ((ushort4*)(xb + (size_t)bt * CC))[tid] = ub;
}

// ---------------- GEMM v2: 256x128 tile, 8 waves (4Mx2N), BK=64 ----------------
// LDS: double-buffered A[256][64] + B[128][64] bf16 = 96KB dynamic.
// T2 swizzle via G21: linear gload_lds dest, source column-chunk pre-XORed by (row&7),
// reads XOR back -> uniform 8 lanes per 4-bank group (optimal).
// T4: counted s_waitcnt vmcnt(6), raw s_barrier (no vmcnt drain at barriers).
// T5: setprio around MFMA cluster.
template<int EPI>
__global__ __launch_bounds__(512, 1) void gemm2_kernel(
    const unsigned short* __restrict__ A,   // M x K bf16
    const unsigned short* __restrict__ W,   // N x K bf16
    float* __restrict__ xres,
    unsigned short* __restrict__ outb,
    const float* __restrict__ bias,
    int K, int N) {
  extern __shared__ unsigned short lds[];   // [2][256*64] A, then [2][128*64] B
  const int tid = threadIdx.x;
  const int wv = tid >> 6, ln = tid & 63;
  const int g = ln >> 4, r = ln & 15;
  const int wm = wv >> 1, wn = wv & 1;

  // XCD-aware swizzle (nwg % 8 == 0 for all our shapes)
  const int nwg = gridDim.x;
  const int bid = blockIdx.x;
  const int swz = (bid & 7) * (nwg >> 3) + (bid >> 3);
  const int by = swz & 31;            // M blocks = 8192/256 = 32
  const int bx = swz >> 5;            // N blocks
  const int brow = by * 256, bcol = bx * 128;

  // staging source pointers (per-thread, column pre-swizzled)
  const unsigned short* asrc[4];
  const unsigned short* bsrc[2];
  #pragma unroll
  for (int rd = 0; rd < 4; ++rd) {
    int ch = rd * 512 + tid;
    int row = ch >> 3, c = (ch & 7) ^ (row & 7);
    asrc[rd] = A + (size_t)(brow + row) * K + c * 8;
  }
  #pragma unroll
  for (int rd = 0; rd < 2; ++rd) {
    int ch = rd * 512 + tid;
    int row = ch >> 3, c = (ch & 7) ^ (row & 7);
    bsrc[rd] = W + (size_t)(bcol + row) * K + c * 8;
  }
  unsigned short* Abase = lds;             // 2 x 16384 shorts
  unsigned short* Bbase = lds + 32768;     // 2 x 8192 shorts

  auto stage = [&](int tk) {
    unsigned short* Ad = Abase + (tk & 1) * 16384 + wv * 512;
    unsigned short* Bd = Bbase + (tk & 1) * 8192 + wv * 512;
    int ko = tk * 64;
    #pragma unroll
    for (int rd = 0; rd < 4; ++rd) gload16(asrc[rd] + ko, Ad + rd * 4096);
    #pragma unroll
    for (int rd = 0; rd < 2; ++rd) gload16(bsrc[rd] + ko, Bd + rd * 4096);
  };

  f32x4 acc[4][4];
  #pragma unroll
  for (int i = 0; i < 4; ++i)
    #pragma unroll
    for (int j = 0; j < 4; ++j)
      acc[i][j] = (f32x4){0.f, 0.f, 0.f, 0.f};

  stage(0);
  const int NT = K >> 6;
  for (int t = 0; t < NT; ++t) {
    if (t + 1 < NT) {
      stage(t + 1);
      asm volatile("s_waitcnt vmcnt(6)" ::: "memory");
    } else {
      asm volatile("s_waitcnt vmcnt(0)" ::: "memory");
    }
    __builtin_amdgcn_s_barrier();
    __builtin_amdgcn_sched_barrier(0);

    const unsigned short* Ab = Abase + (t & 1) * 16384;
    const unsigned short* Bb = Bbase + (t & 1) * 8192;
    bf16x8 av[2][4], bv[2][4];
    #pragma unroll
    for (int kk = 0; kk < 2; ++kk) {
      int chx = ((kk * 4 + g) ^ (r & 7)) << 3;   // swizzled chunk (shorts)
      #pragma unroll
      for (int i = 0; i < 4; ++i) {
        av[kk][i] = *(const bf16x8*)(Ab + (wm * 64 + i * 16 + r) * 64 + chx);
        bv[kk][i] = *(const bf16x8*)(Bb + (wn * 64 + i * 16 + r) * 64 + chx);
      }
    }
    __builtin_amdgcn_s_setprio(1);
    #pragma unroll
    for (int kk = 0; kk < 2; ++kk)
      #pragma unroll
      for (int i = 0; i < 4; ++i)
        #pragma unroll
        for (int j = 0; j < 4; ++j)
          acc[i][j] = __builtin_amdgcn_mfma_f32_16x16x32_bf16(av[kk][i], bv[kk][j], acc[i][j], 0, 0, 0);
    __builtin_amdgcn_s_setprio(0);
    __builtin_amdgcn_sched_barrier(0);
    __builtin_amdgcn_s_barrier();
  }

  // epilogue
  #pragma unroll
  for (int i = 0; i < 4; ++i) {
    #pragma unroll
    for (int j = 0; j < 4; ++j) {
      #pragma unroll
      for (int q = 0; q < 4; ++q) {
        int rowg = brow + wm * 64 + i * 16 + g * 4 + q;
        int colg = bcol + wn * 64 + j * 16 + r;
        size_t off = (size_t)rowg * N + colg;
        float vacc = acc[i][j][q];
        if (EPI == 0) {
          outb[off] = f2b(vacc);
        } else if (EPI == 1) {
          float nx = xres[off] + vacc;
          xres[off] = nx; outb[off] = f2b(nx);
        } else if (EPI == 2) {
          float hv = vacc + bias[colg];
          hv = hv > 0.f ? hv : 0.f;
          outb[off] = f2b(hv);
        } else {
          float nx = xres[off] + vacc + bias[colg];
          xres[off] = nx; outb[off] = f2b(nx);
        }
      }
    }
  }
}

// ---------------- MFMA flash attention (unchanged from R2) ----------------
template<int E>
__device__ __forceinline__ bf16x8 buildP(const f32x16& p) {
  uint32_t a = pkbf(p[E + 0], p[E + 1]);
  uint32_t b = pkbf(p[E + 4], p[E + 5]);
  uint32_t c = pkbf(p[E + 2], p[E + 3]);
  uint32_t d = pkbf(p[E + 6], p[E + 7]);
  asm("v_permlane32_swap_b32 %0, %1" : "+v"(a), "+v"(b));
  asm("v_permlane32_swap_b32 %0, %1" : "+v"(c), "+v"(d));
  union { uint32_t u[4]; bf16x8 v; } r;
  r.u[0] = a; r.u[1] = c; r.u[2] = b; r.u[3] = d;
  return r.v;
}

__global__ __launch_bounds__(256) void attn_kernel(const unsigned short* __restrict__ qkv,
                                                   unsigned short* __restrict__ ob) {
  __shared__ unsigned short Kl[64 * 64];
  __shared__ unsigned short Vt[64 * 64];
  const int tid = threadIdx.x;
  const int wv = tid >> 6, ln = tid & 63;
  const int lq = ln & 31, hi = ln >> 5;
  const int qt = blockIdx.x >> 8, bh = blockIdx.x & 255;
  const int b = bh >> 4, h = bh & 15;
  const int qrow = qt * 128 + wv * 32 + lq;
  const size_t rowQ = (size_t)(b * TT + qrow) * 3072 + h * 64;

  const float cs = 0.125f * 1.44269504f;
  bf16x8 qf[4];
  #pragma unroll
  for (int t = 0; t < 4; ++t) {
    uint4 u = *(const uint4*)(qkv + rowQ + t * 16 + hi * 8);
    uint32_t w[4] = {u.x, u.y, u.z, u.w};
    union { uint32_t u4[4]; bf16x8 v; } cv;
    #pragma unroll
    for (int j = 0; j < 4; ++j) cv.u4[j] = pkbf(blo(w[j]) * cs, bhi(w[j]) * cs);
    qf[t] = cv.v;
  }

  f32x16 o0 = {}, o1 = {};
  float mrun = -3.0e38f, lsum = 0.f;

  for (int kv0 = 0; kv0 < TT; kv0 += 64) {
    if (kv0) __syncthreads();
    #pragma unroll
    for (int r = 0; r < 2; ++r) {
      int ch = r * 256 + tid;
      int k = ch >> 3, cc = ch & 7;
      int sg = (k & 7) ^ (k >> 3);
      const unsigned short* gs = qkv + (size_t)(b * TT + kv0 + k) * 3072 + 1024 + h * 64 + ((cc ^ sg) << 3);
      gload16(gs, Kl + (size_t)(r * 256 + wv * 64) * 8);
    }
    {
      int cc = tid & 7, kp = tid >> 3;
      int k = kp * 2;
      const unsigned short* gv = qkv + (size_t)(b * TT + kv0 + k) * 3072 + 2048 + h * 64 + cc * 8;
      uint4 g1 = *(const uint4*)gv;
      uint4 g2 = *(const uint4*)(gv + 3072);
      uint32_t w1[4] = {g1.x, g1.y, g1.z, g1.w}, w2[4] = {g2.x, g2.y, g2.z, g2.w};
      #pragma unroll
      for (int j = 0; j < 8; ++j) {
        int d = cc * 8 + j;
        uint32_t dw = (j & 1) ? ((w1[j >> 1] >> 16) | (w2[j >> 1] & 0xFFFF0000u))
                              : ((w1[j >> 1] & 0xFFFFu) | (w2[j >> 1] << 16));
        int sg = (d & 7) ^ (d >> 3);
        *(uint32_t*)(Vt + d * 64 + (k ^ (sg << 3))) = dw;
      }
    }
    __syncthreads();

    f32x16 s0 = {}, s1 = {};
    #pragma unroll
    for (int t = 0; t < 4; ++t) {
      int r0 = lq, r1 = 32 + lq;
      bf16x8 a0 = *(const bf16x8*)(Kl + r0 * 64 + ((((t << 1) | hi) ^ ((r0 & 7) ^ (r0 >> 3))) << 3));
      bf16x8 a1 = *(const bf16x8*)(Kl + r1 * 64 + ((((t << 1) | hi) ^ ((r1 & 7) ^ (r1 >> 3))) << 3));
      s0 = __builtin_amdgcn_mfma_f32_32x32x16_bf16(a0, qf[t], s0, 0, 0, 0);
      s1 = __builtin_amdgcn_mfma_f32_32x32x16_bf16(a1, qf[t], s1, 0, 0, 0);
    }

    float mx = s0[0];
    #pragma unroll
    for (int r = 1; r < 16; ++r) mx = fmaxf(mx, s0[r]);
    #pragma unroll
    for (int r = 0; r < 16; ++r) mx = fmaxf(mx, s1[r]);
    mx = fmaxf(mx, __shfl_xor(mx, 32));
    float mnew = fmaxf(mrun, mx);
    float cf = ex2(mrun - mnew);
    mrun = mnew;
    lsum *= cf;
    #pragma unroll
    for (int r = 0; r < 16; ++r) { o0[r] *= cf; o1[r] *= cf; }
    #pragma unroll
    for (int r = 0; r < 16; ++r) {
      s0[r] = ex2(s0[r] - mnew);
      s1[r] = ex2(s1[r] - mnew);
      lsum += s0[r] + s1[r];
    }

    bf16x8 pf0 = buildP<0>(s0);
    bf16x8 pf1 = buildP<8>(s0);
    bf16x8 pf2 = buildP<0>(s1);
    bf16x8 pf3 = buildP<8>(s1);

    #pragma unroll
    for (int t = 0; t < 4; ++t) {
      bf16x8 pf = (t == 0) ? pf0 : (t == 1) ? pf1 : (t == 2) ? pf2 : pf3;
      int d0 = lq, d1 = 32 + lq;
      bf16x8 v0 = *(const bf16x8*)(Vt + d0 * 64 + ((((t << 1) | hi) ^ ((d0 & 7) ^ (d0 >> 3))) << 3));
      bf16x8 v1 = *(const bf16x8*)(Vt + d1 * 64 + ((((t << 1) | hi) ^ ((d1 & 7) ^ (d1 >> 3))) << 3));
      o0 = __builtin_amdgcn_mfma_f32_32x32x16_bf16(v0, pf, o0, 0, 0, 0);
      o1 = __builtin_amdgcn_mfma_f32_32x32x16_bf16(v1, pf, o1, 0, 0, 0);
    }
  }

  lsum += __shfl_xor(lsum, 32);
  float inv = 1.f / lsum;
  size_t orow = (size_t)(b * TT + qrow) * CC + h * 64;
  #pragma unroll
  for (int md = 0; md < 2; ++md) {
    #pragma unroll
    for (int rq = 0; rq < 4; ++rq) {
      int d0 = md * 32 + rq * 8 + hi * 4;
      float e0 = (md ? o1[rq * 4 + 0] : o0[rq * 4 + 0]) * inv;
      float e1 = (md ? o1[rq * 4 + 1] : o0[rq * 4 + 1]) * inv;
      float e2 = (md ? o1[rq * 4 + 2] : o0[rq * 4 + 2]) * inv;
      float e3 = (md ? o1[rq * 4 + 3] : o0[rq * 4 + 3]) * inv;
      uint2 st; st.x = pkbf(e0, e1); st.y = pkbf(e2, e3);
      *(uint2*)(ob + orow + d0) = st;
    }
  }
}

// ---------------- final: out[b,c] = sum_t x[b,t,c] * I[b,t] ----------------
__global__ __launch_bounds__(256) void final_kernel(const float* __restrict__ x,
                                                    const float* __restrict__ I,
                                                    float* __restrict__ out) {
  int b = blockIdx.x >> 2;
  int c = ((blockIdx.x & 3) << 8) + threadIdx.x;
  float acc = 0.f;
  const float* xp = x + (size_t)b * TT * CC + c;
  const float* Ip = I + (size_t)b * TT;
  for (int t = 0; t < TT; ++t) acc = fmaf(xp[(size_t)t * CC], Ip[t], acc);
  out[b * CC + c] = acc;
}

extern "C" void kernel_launch(void* const* d_in, const int* in_sizes, int n_in,
                              void* d_out, int out_size, void* d_ws, size_t ws_size,
                              hipStream_t stream) {
  const int*   X      = (const int*)d_in[0];
  const float* I      = (const float*)d_in[1];
  const int*   S      = (const int*)d_in[2];
  const float* emb    = (const float*)d_in[3];
  const float* pos    = (const float*)d_in[4];
  const float* qkv_w  = (const float*)d_in[5];
  const float* out_w  = (const float*)d_in[6];
  const float* ffn_w1 = (const float*)d_in[7];
  const float* ffn_b1 = (const float*)d_in[8];
  const float* ffn_w2 = (const float*)d_in[9];
  const float* ffn_b2 = (const float*)d_in[10];
  float* out = (float*)d_out;

  char* ws = (char*)d_ws;
  size_t off = 0;
  auto walloc = [&](size_t bytes) { char* p = ws + off; off += (bytes + 255) & ~(size_t)255; return p; };
  unsigned short* wqkv = (unsigned short*)walloc((size_t)LAYERS * 3 * CC * CC * 2);
  unsigned short* wo   = (unsigned short*)walloc((size_t)LAYERS * CC * CC * 2);
  unsigned short* w1   = (unsigned short*)walloc((size_t)LAYERS * CC * CC * 2);
  unsigned short* w2   = (unsigned short*)walloc((size_t)LAYERS * CC * CC * 2);
  float*          x    = (float*)walloc((size_t)MM * CC * 4);
  unsigned short* xb   = (unsigned short*)walloc((size_t)MM * CC * 2);
  unsigned short* qkvb = (unsigned short*)walloc((size_t)MM * 3 * CC * 2);
  unsigned short* obuf = (unsigned short*)walloc((size_t)MM * CC * 2);
  unsigned short* hbuf = (unsigned short*)walloc((size_t)MM * CC * 2);
  if (off > ws_size) return;

  int n4;
  n4 = LAYERS * 3 * CC * CC / 4; cvt_kernel<<<(n4 + 255) / 256, 256, 0, stream>>>(qkv_w, wqkv, n4);
  n4 = LAYERS * CC * CC / 4;     cvt_kernel<<<(n4 + 255) / 256, 256, 0, stream>>>(out_w, wo, n4);
  n4 = LAYERS * CC * CC / 4;     cvt_kernel<<<(n4 + 255) / 256, 256, 0, stream>>>(ffn_w1, w1, n4);
  n4 = LAYERS * CC * CC / 4;     cvt_kernel<<<(n4 + 255) / 256, 256, 0, stream>>>(ffn_w2, w2, n4);

  embed_kernel<<<MM, 256, 0, stream>>>(X, S, emb, pos, x, xb);

  const size_t ldsB = 96 * 1024;
  for (int l = 0; l < LAYERS; ++l) {
    gemm2_kernel<0><<<(MM / 256) * (3 * CC / 128), 512, ldsB, stream>>>(
        xb, wqkv + (size_t)l * 3 * CC * CC, nullptr, qkvb, nullptr, CC, 3 * CC);
    attn_kernel<<<4 * 256, 256, 0, stream>>>(qkvb, obuf);
    gemm2_kernel<1><<<(MM / 256) * (CC / 128), 512, ldsB, stream>>>(
        obuf, wo + (size_t)l * CC * CC, x, xb, nullptr, CC, CC);
    gemm2_kernel<2><<<(MM / 256) * (CC / 128), 512, ldsB, stream>>>(
        xb, w1 + (size_t)l * CC * CC, nullptr, hbuf, ffn_b1 + l * CC, CC, CC);
    gemm2_kernel<3><<<(MM / 256) * (CC / 128), 512, ldsB, stream>>>(
        hbuf, w2 + (size_t)l * CC * CC, x, xb, ffn_b2 + l * CC, CC, CC);
  }

  final_kernel<<<BB * 4, 256, 0, stream>>>(x, I, out);
}